// Round 6
// baseline (451.566 us; speedup 1.0000x reference)
//
#include <hip/hip_runtime.h>
#include <hip/hip_cooperative_groups.h>
#include <math.h>

namespace cg = cooperative_groups;

#define N 8192
#define FIN 129
#define D 64
#define TEMP 10.0f
#define LOG2E 1.4426950408889634f

// fused kernel geometry: 256 blocks x 1024 thr (16 waves) = 4096 waves
#define NBLK 256
#define WPB 16
#define JS 8                  // j-slices per row-tile
#define JSW (N / JS)          // 1024 cols per wave slice
#define CFI (JSW / 32)        // 32 inner iterations
// fallback geometry
#define SPLIT 16

typedef _Float16 f16x8 __attribute__((ext_vector_type(8)));
typedef float    f32x4 __attribute__((ext_vector_type(4)));

#define MFMA16(A, B, C) __builtin_amdgcn_mfma_f32_16x16x32_f16((A), (B), (C), 0, 0, 0)

// ============================================================================
// Fused cooperative kernel: 5 phases over grid.sync().
// Wave geometry for N^2 phases (swapped operands: A=k-rows, B=q-rows):
//   gw = blockIdx.x*16+wave (0..4095); row-tile = gw>>3 (16 rows, i=i0+lr);
//   j-slice = gw&7 (1024 cols). A lane's 8 scores per 32-col step all belong
//   to the SAME output row i -> cheap row max/sum, float4 column stores.
// ============================================================================
__global__ __launch_bounds__(1024, 4) void k_fused(
    const float* __restrict__ x,
    const float* __restrict__ Wq1, const float* __restrict__ bq1,
    const float* __restrict__ Wq2, const float* __restrict__ bq2,
    const float* __restrict__ Wk1, const float* __restrict__ bk1,
    const float* __restrict__ Wk2, const float* __restrict__ bk2,
    _Float16* __restrict__ q16, _Float16* __restrict__ k16,
    float* __restrict__ mpart, float* __restrict__ M2part, float* __restrict__ Lpart,
    float* __restrict__ rinv, float* __restrict__ M2, float* __restrict__ Linv,
    float* __restrict__ out)
{
    cg::grid_group grid = cg::this_grid();
    const int tid  = threadIdx.x;
    const int wave = tid >> 6;
    const int lane = tid & 63;
    const int lr   = lane & 15;
    const int lg   = lane >> 4;
    const int gw   = blockIdx.x * WPB + wave;

    __shared__ float xs[WPB][FIN + 3];
    __shared__ float hqs[WPB][D];
    __shared__ float hks[WPB][D];

    // ---------------- P0: MLP -> q16, k16 (2 rows per wave) ----------------
    for (int rr = 0; rr < 2; ++rr) {
        const int row = gw * 2 + rr;
        const float* xr = x + (size_t)row * FIN;
        xs[wave][lane]      = xr[lane];
        xs[wave][64 + lane] = xr[64 + lane];
        if (lane == 0) xs[wave][128] = xr[128];
        __syncthreads();
        float aq = bq1[lane], ak = bk1[lane];
        for (int f = 0; f < FIN; ++f) {
            const float xv = xs[wave][f];
            aq = fmaf(xv, Wq1[f * D + lane], aq);
            ak = fmaf(xv, Wk1[f * D + lane], ak);
        }
        hqs[wave][lane] = fmaxf(aq, 0.f);
        hks[wave][lane] = fmaxf(ak, 0.f);
        __syncthreads();
        float oq = bq2[lane], ok = bk2[lane];
        for (int t = 0; t < D; ++t) {
            oq = fmaf(hqs[wave][t], Wq2[t * D + lane], oq);
            ok = fmaf(hks[wave][t], Wk2[t * D + lane], ok);
        }
        q16[(size_t)row * D + lane] = (_Float16)oq;
        k16[(size_t)row * D + lane] = (_Float16)ok;
        __syncthreads();
    }
    grid.sync();

    const int i0    = (gw >> 3) * 16;
    const int jbase = (gw & 7) * JSW;
    const f16x8 b0 = *reinterpret_cast<const f16x8*>(&q16[(i0 + lr) * D + 8 * lg]);
    const f16x8 b1 = *reinterpret_cast<const f16x8*>(&q16[(i0 + lr) * D + 32 + 8 * lg]);

    // ---------------- P1: raw row max -> mpart[JS][N] ----------------
    {
        float mx = -INFINITY;
        for (int cf = 0; cf < CFI; ++cf) {
            const int j0 = jbase + cf * 32;
            #pragma unroll
            for (int rf = 0; rf < 2; ++rf) {
                const f16x8 a0 = *reinterpret_cast<const f16x8*>(&k16[(j0 + rf * 16 + lr) * D + 8 * lg]);
                const f16x8 a1 = *reinterpret_cast<const f16x8*>(&k16[(j0 + rf * 16 + lr) * D + 32 + 8 * lg]);
                f32x4 acc = {0.f, 0.f, 0.f, 0.f};
                acc = MFMA16(a0, b0, acc);
                acc = MFMA16(a1, b1, acc);
                mx = fmaxf(mx, fmaxf(fmaxf(acc[0], acc[1]), fmaxf(acc[2], acc[3])));
            }
        }
        mx = fmaxf(mx, __shfl_xor(mx, 16));
        mx = fmaxf(mx, __shfl_xor(mx, 32));
        if (lane < 16) mpart[(gw & 7) * N + i0 + lr] = mx;
    }
    grid.sync();

    // ---------------- fin1: rinv[j] = TEMP*log2e / m_j ----------------
    if (blockIdx.x < N / 1024) {
        const int j = blockIdx.x * 1024 + tid;
        float m = mpart[j];
        #pragma unroll
        for (int s = 1; s < JS; ++s) m = fmaxf(m, mpart[s * N + j]);
        rinv[j] = TEMP * LOG2E / m;
    }
    grid.sync();

    // ---------------- P2: scaled row max + sum -> M2part, Lpart ----------------
    {
        float mx = -INFINITY, sm = 0.f;
        for (int cf = 0; cf < CFI; ++cf) {
            const int j0 = jbase + cf * 32;
            float s[8];
            #pragma unroll
            for (int rf = 0; rf < 2; ++rf) {
                const f16x8 a0 = *reinterpret_cast<const f16x8*>(&k16[(j0 + rf * 16 + lr) * D + 8 * lg]);
                const f16x8 a1 = *reinterpret_cast<const f16x8*>(&k16[(j0 + rf * 16 + lr) * D + 32 + 8 * lg]);
                const float4 r4 = *reinterpret_cast<const float4*>(&rinv[j0 + rf * 16 + lg * 4]);
                f32x4 acc = {0.f, 0.f, 0.f, 0.f};
                acc = MFMA16(a0, b0, acc);
                acc = MFMA16(a1, b1, acc);
                s[rf * 4 + 0] = acc[0] * r4.x;
                s[rf * 4 + 1] = acc[1] * r4.y;
                s[rf * 4 + 2] = acc[2] * r4.z;
                s[rf * 4 + 3] = acc[3] * r4.w;
            }
            const float tm = fmaxf(fmaxf(fmaxf(s[0], s[1]), fmaxf(s[2], s[3])),
                                   fmaxf(fmaxf(s[4], s[5]), fmaxf(s[6], s[7])));
            const float nm = fmaxf(mx, tm);
            float add = 0.f;
            #pragma unroll
            for (int t = 0; t < 8; ++t) add += exp2f(s[t] - nm);
            sm = fmaf(sm, exp2f(mx - nm), add);
            mx = nm;
        }
        #pragma unroll
        for (int off = 16; off <= 32; off <<= 1) {
            const float om = __shfl_xor(mx, off);
            const float os = __shfl_xor(sm, off);
            const float nm = fmaxf(mx, om);
            sm = sm * exp2f(mx - nm) + os * exp2f(om - nm);
            mx = nm;
        }
        if (lane < 16) {
            M2part[(gw & 7) * N + i0 + lr] = mx;
            Lpart [(gw & 7) * N + i0 + lr] = sm;
        }
    }
    grid.sync();

    // ---------------- finML: M2[i], Linv[i] ----------------
    if (blockIdx.x < N / 1024) {
        const int i = blockIdx.x * 1024 + tid;
        float M = M2part[i];
        #pragma unroll
        for (int s = 1; s < JS; ++s) M = fmaxf(M, M2part[s * N + i]);
        float L = 0.f;
        #pragma unroll
        for (int s = 0; s < JS; ++s) L += Lpart[s * N + i] * exp2f(M2part[s * N + i] - M);
        M2[i] = M;
        Linv[i] = 1.f / L;
    }
    grid.sync();

    // ---------------- P3: out = exp2(s2 - M2_i) * Linv_i ----------------
    {
        const float M2i = M2[i0 + lr];
        const float Lvi = Linv[i0 + lr];
        float* rowp = out + (size_t)(i0 + lr) * N;
        for (int cf = 0; cf < CFI; ++cf) {
            const int j0 = jbase + cf * 32;
            #pragma unroll
            for (int rf = 0; rf < 2; ++rf) {
                const f16x8 a0 = *reinterpret_cast<const f16x8*>(&k16[(j0 + rf * 16 + lr) * D + 8 * lg]);
                const f16x8 a1 = *reinterpret_cast<const f16x8*>(&k16[(j0 + rf * 16 + lr) * D + 32 + 8 * lg]);
                const float4 r4 = *reinterpret_cast<const float4*>(&rinv[j0 + rf * 16 + lg * 4]);
                f32x4 acc = {0.f, 0.f, 0.f, 0.f};
                acc = MFMA16(a0, b0, acc);
                acc = MFMA16(a1, b1, acc);
                float4 o;
                o.x = exp2f(fmaf(acc[0], r4.x, -M2i)) * Lvi;
                o.y = exp2f(fmaf(acc[1], r4.y, -M2i)) * Lvi;
                o.z = exp2f(fmaf(acc[2], r4.z, -M2i)) * Lvi;
                o.w = exp2f(fmaf(acc[3], r4.w, -M2i)) * Lvi;
                *reinterpret_cast<float4*>(&rowp[j0 + rf * 16 + lg * 4]) = o;
            }
        }
    }
}

// ============================================================================
// Fallback path (R4 kernels, correctness-proven) — used only if the
// cooperative launch is rejected.
// ============================================================================
__global__ __launch_bounds__(256) void k_mlp(
    const float* __restrict__ x,
    const float* __restrict__ Wq1, const float* __restrict__ bq1,
    const float* __restrict__ Wq2, const float* __restrict__ bq2,
    const float* __restrict__ Wk1, const float* __restrict__ bk1,
    const float* __restrict__ Wk2, const float* __restrict__ bk2,
    _Float16* __restrict__ qo, _Float16* __restrict__ ko)
{
    __shared__ float xs[4][FIN];
    __shared__ float hqs[4][D];
    __shared__ float hks[4][D];
    const int wave = threadIdx.x >> 6;
    const int lane = threadIdx.x & 63;
    const int row  = (blockIdx.x << 2) + wave;

    const float* xr = x + row * FIN;
    xs[wave][lane]      = xr[lane];
    xs[wave][64 + lane] = xr[64 + lane];
    if (lane == 0) xs[wave][128] = xr[128];
    __syncthreads();

    float aq = bq1[lane], ak = bk1[lane];
    for (int f = 0; f < FIN; ++f) {
        const float xv = xs[wave][f];
        aq = fmaf(xv, Wq1[f * D + lane], aq);
        ak = fmaf(xv, Wk1[f * D + lane], ak);
    }
    hqs[wave][lane] = fmaxf(aq, 0.f);
    hks[wave][lane] = fmaxf(ak, 0.f);
    __syncthreads();

    float oq = bq2[lane], ok = bk2[lane];
    for (int t = 0; t < D; ++t) {
        oq = fmaf(hqs[wave][t], Wq2[t * D + lane], oq);
        ok = fmaf(hks[wave][t], Wk2[t * D + lane], ok);
    }
    qo[row * D + lane] = (_Float16)oq;
    ko[row * D + lane] = (_Float16)ok;
}

__global__ __launch_bounds__(256) void k_max(
    const _Float16* __restrict__ q16, const _Float16* __restrict__ k16,
    float* __restrict__ mpart)
{
    const int tid = threadIdx.x;
    const int wave = tid >> 6, lane = tid & 63, lr = lane & 15, lg = lane >> 4;
    const int iw = blockIdx.x * 64 + wave * 16;
    const int jbase = blockIdx.y * (N / SPLIT);

    f16x8 b0 = *reinterpret_cast<const f16x8*>(&q16[(iw + lr) * D + 8 * lg]);
    f16x8 b1 = *reinterpret_cast<const f16x8*>(&q16[(iw + lr) * D + 32 + 8 * lg]);

    float mx = -INFINITY;
    for (int cf = 0; cf < (N / SPLIT) / 32; ++cf) {
        const int j0 = jbase + cf * 32;
        #pragma unroll
        for (int rf = 0; rf < 2; ++rf) {
            const f16x8 a0 = *reinterpret_cast<const f16x8*>(&k16[(j0 + rf * 16 + lr) * D + 8 * lg]);
            const f16x8 a1 = *reinterpret_cast<const f16x8*>(&k16[(j0 + rf * 16 + lr) * D + 32 + 8 * lg]);
            f32x4 acc = {0.f, 0.f, 0.f, 0.f};
            acc = MFMA16(a0, b0, acc);
            acc = MFMA16(a1, b1, acc);
            mx = fmaxf(mx, fmaxf(fmaxf(acc[0], acc[1]), fmaxf(acc[2], acc[3])));
        }
    }
    mx = fmaxf(mx, __shfl_xor(mx, 16));
    mx = fmaxf(mx, __shfl_xor(mx, 32));
    if (lane < 16) mpart[blockIdx.y * N + iw + lr] = mx;
}

__global__ __launch_bounds__(256) void k_fin1(const float* __restrict__ mp, float* __restrict__ rinv)
{
    const int j = blockIdx.x * 256 + threadIdx.x;
    float m = mp[j];
    #pragma unroll
    for (int s = 1; s < SPLIT; ++s) m = fmaxf(m, mp[s * N + j]);
    rinv[j] = TEMP * LOG2E / m;
}

__global__ __launch_bounds__(256) void k_sumL(
    const _Float16* __restrict__ q16, const _Float16* __restrict__ k16,
    const float* __restrict__ rinv,
    float* __restrict__ M2part, float* __restrict__ Lpart)
{
    const int tid = threadIdx.x;
    const int wave = tid >> 6, lane = tid & 63, lr = lane & 15, lg = lane >> 4;
    const int iw = blockIdx.x * 64 + wave * 16;
    const int jbase = blockIdx.y * (N / SPLIT);

    f16x8 b0 = *reinterpret_cast<const f16x8*>(&q16[(iw + lr) * D + 8 * lg]);
    f16x8 b1 = *reinterpret_cast<const f16x8*>(&q16[(iw + lr) * D + 32 + 8 * lg]);

    float mx = -INFINITY, sm = 0.f;
    for (int cf = 0; cf < (N / SPLIT) / 32; ++cf) {
        const int j0 = jbase + cf * 32;
        float s[8];
        #pragma unroll
        for (int rf = 0; rf < 2; ++rf) {
            const f16x8 a0 = *reinterpret_cast<const f16x8*>(&k16[(j0 + rf * 16 + lr) * D + 8 * lg]);
            const f16x8 a1 = *reinterpret_cast<const f16x8*>(&k16[(j0 + rf * 16 + lr) * D + 32 + 8 * lg]);
            const float4 r4 = *reinterpret_cast<const float4*>(&rinv[j0 + rf * 16 + lg * 4]);
            f32x4 acc = {0.f, 0.f, 0.f, 0.f};
            acc = MFMA16(a0, b0, acc);
            acc = MFMA16(a1, b1, acc);
            s[rf * 4 + 0] = acc[0] * r4.x;
            s[rf * 4 + 1] = acc[1] * r4.y;
            s[rf * 4 + 2] = acc[2] * r4.z;
            s[rf * 4 + 3] = acc[3] * r4.w;
        }
        const float tm = fmaxf(fmaxf(fmaxf(s[0], s[1]), fmaxf(s[2], s[3])),
                               fmaxf(fmaxf(s[4], s[5]), fmaxf(s[6], s[7])));
        const float nm = fmaxf(mx, tm);
        float add = 0.f;
        #pragma unroll
        for (int t = 0; t < 8; ++t) add += exp2f(s[t] - nm);
        sm = fmaf(sm, exp2f(mx - nm), add);
        mx = nm;
    }
    #pragma unroll
    for (int off = 16; off <= 32; off <<= 1) {
        const float om = __shfl_xor(mx, off);
        const float os = __shfl_xor(sm, off);
        const float nm = fmaxf(mx, om);
        sm = sm * exp2f(mx - nm) + os * exp2f(om - nm);
        mx = nm;
    }
    if (lane < 16) {
        M2part[blockIdx.y * N + iw + lr] = mx;
        Lpart [blockIdx.y * N + iw + lr] = sm;
    }
}

__global__ __launch_bounds__(256) void k_finML(
    const float* __restrict__ M2p, const float* __restrict__ Lp,
    float* __restrict__ M2, float* __restrict__ Linv)
{
    const int i = blockIdx.x * 256 + threadIdx.x;
    float M = M2p[i];
    #pragma unroll
    for (int s = 1; s < SPLIT; ++s) M = fmaxf(M, M2p[s * N + i]);
    float L = 0.f;
    #pragma unroll
    for (int s = 0; s < SPLIT; ++s) L += Lp[s * N + i] * exp2f(M2p[s * N + i] - M);
    M2[i] = M;
    Linv[i] = 1.f / L;
}

__global__ __launch_bounds__(256) void k_write(
    const _Float16* __restrict__ q16, const _Float16* __restrict__ k16,
    const float* __restrict__ rinv, const float* __restrict__ M2,
    const float* __restrict__ Linv, float* __restrict__ out)
{
    const int tid = threadIdx.x;
    const int wave = tid >> 6, lane = tid & 63, lr = lane & 15, lg = lane >> 4;
    const int iw = blockIdx.x * 64 + wave * 16;
    const int jbase = blockIdx.y * 256;

    f16x8 b0 = *reinterpret_cast<const f16x8*>(&q16[(iw + lr) * D + 8 * lg]);
    f16x8 b1 = *reinterpret_cast<const f16x8*>(&q16[(iw + lr) * D + 32 + 8 * lg]);
    const float M2i = M2[iw + lr];
    const float Lvi = Linv[iw + lr];
    float* rowp = out + (size_t)(iw + lr) * N;

    #pragma unroll
    for (int cf = 0; cf < 8; ++cf) {
        const int j0 = jbase + cf * 32;
        #pragma unroll
        for (int rf = 0; rf < 2; ++rf) {
            const f16x8 a0 = *reinterpret_cast<const f16x8*>(&k16[(j0 + rf * 16 + lr) * D + 8 * lg]);
            const f16x8 a1 = *reinterpret_cast<const f16x8*>(&k16[(j0 + rf * 16 + lr) * D + 32 + 8 * lg]);
            const float4 r4 = *reinterpret_cast<const float4*>(&rinv[j0 + rf * 16 + lg * 4]);
            f32x4 acc = {0.f, 0.f, 0.f, 0.f};
            acc = MFMA16(a0, b0, acc);
            acc = MFMA16(a1, b1, acc);
            float4 o;
            o.x = exp2f(fmaf(acc[0], r4.x, -M2i)) * Lvi;
            o.y = exp2f(fmaf(acc[1], r4.y, -M2i)) * Lvi;
            o.z = exp2f(fmaf(acc[2], r4.z, -M2i)) * Lvi;
            o.w = exp2f(fmaf(acc[3], r4.w, -M2i)) * Lvi;
            *reinterpret_cast<float4*>(&rowp[j0 + rf * 16 + lg * 4]) = o;
        }
    }
}

extern "C" void kernel_launch(void* const* d_in, const int* in_sizes, int n_in,
                              void* d_out, int out_size, void* d_ws, size_t ws_size,
                              hipStream_t stream)
{
    const float* x   = (const float*)d_in[0];
    const float* Wq1 = (const float*)d_in[1];
    const float* bq1 = (const float*)d_in[2];
    const float* Wq2 = (const float*)d_in[3];
    const float* bq2 = (const float*)d_in[4];
    const float* Wk1 = (const float*)d_in[5];
    const float* bk1 = (const float*)d_in[6];
    const float* Wk2 = (const float*)d_in[7];
    const float* bk2 = (const float*)d_in[8];

    float* out = (float*)d_out;

    _Float16* q16 = (_Float16*)d_ws;                       // 1 MB
    _Float16* k16 = q16 + (size_t)N * D;                   // 1 MB
    float* mpart  = (float*)(k16 + (size_t)N * D);         // SPLIT*N (fused uses first 8 rows)
    float* M2part = mpart + (size_t)SPLIT * N;
    float* Lpart  = M2part + (size_t)SPLIT * N;
    float* rinv   = Lpart + (size_t)SPLIT * N;             // N
    float* M2     = rinv + N;                              // N
    float* Linv   = M2 + N;                                // N

    void* args[] = {
        (void*)&x, (void*)&Wq1, (void*)&bq1, (void*)&Wq2, (void*)&bq2,
        (void*)&Wk1, (void*)&bk1, (void*)&Wk2, (void*)&bk2,
        (void*)&q16, (void*)&k16,
        (void*)&mpart, (void*)&M2part, (void*)&Lpart,
        (void*)&rinv, (void*)&M2, (void*)&Linv, (void*)&out
    };
    hipError_t err = hipLaunchCooperativeKernel((const void*)k_fused, dim3(NBLK),
                                                dim3(1024), args, 0, stream);
    if (err != hipSuccess) {
        (void)hipGetLastError();   // clear sticky error, use proven multi-kernel path
        k_mlp  <<<N / 4, 256, 0, stream>>>(x, Wq1, bq1, Wq2, bq2, Wk1, bk1, Wk2, bk2, q16, k16);
        k_max  <<<dim3(N / 64, SPLIT), 256, 0, stream>>>(q16, k16, mpart);
        k_fin1 <<<N / 256, 256, 0, stream>>>(mpart, rinv);
        k_sumL <<<dim3(N / 64, SPLIT), 256, 0, stream>>>(q16, k16, rinv, M2part, Lpart);
        k_finML<<<N / 256, 256, 0, stream>>>(M2part, Lpart, M2, Linv);
        k_write<<<dim3(N / 64, N / 256), 256, 0, stream>>>(q16, k16, rinv, M2, Linv, out);
    }
}

// Round 7
// 154.975 us; speedup vs baseline: 2.9138x; 2.9138x over previous
//
#include <hip/hip_runtime.h>
#include <math.h>

#define N 8192
#define FIN 129
#define D 64
#define TEMP 10.0f
#define LOG2E 1.4426950408889634f
#define SPLIT 16              // j-slices for all N^2 passes
#define RG 4                  // row-groups per wave -> 64 rows/wave
#define BROWS 256             // 4 waves * 64 rows

typedef _Float16 f16x8 __attribute__((ext_vector_type(8)));
typedef float    f32x4 __attribute__((ext_vector_type(4)));

#define MFMA16(A, B, C) __builtin_amdgcn_mfma_f32_16x16x32_f16((A), (B), (C), 0, 0, 0)

// Validated geometry (swapped operands, A=k-rows, B=q-rows), from R4-passing code:
//   B-frag: q row i = i0 + rg*16 + lr   (lr = lane&15)  -> lane's output ROW
//   A-frag: k row j = j0 + rf*16 + lr
//   C elem e: col j = j0 + rf*16 + lg*4 + e  (lg = lane>>4)
// Per lane: 4 consecutive output cols of ONE row -> float4 stores, per-element rinv.

// ---------------- Kernel 1: q = mlp_q(x), k = mlp_k(x) -> f16 (validated R2) ----------------
__global__ __launch_bounds__(256) void k_mlp(
    const float* __restrict__ x,
    const float* __restrict__ Wq1, const float* __restrict__ bq1,
    const float* __restrict__ Wq2, const float* __restrict__ bq2,
    const float* __restrict__ Wk1, const float* __restrict__ bk1,
    const float* __restrict__ Wk2, const float* __restrict__ bk2,
    _Float16* __restrict__ qo, _Float16* __restrict__ ko)
{
    __shared__ float xs[4][FIN];
    __shared__ float hqs[4][D];
    __shared__ float hks[4][D];
    const int wave = threadIdx.x >> 6;
    const int lane = threadIdx.x & 63;
    const int row  = (blockIdx.x << 2) + wave;

    const float* xr = x + row * FIN;
    xs[wave][lane]      = xr[lane];
    xs[wave][64 + lane] = xr[64 + lane];
    if (lane == 0) xs[wave][128] = xr[128];
    __syncthreads();

    float aq = bq1[lane], ak = bk1[lane];
    for (int f = 0; f < FIN; ++f) {
        const float xv = xs[wave][f];
        aq = fmaf(xv, Wq1[f * D + lane], aq);
        ak = fmaf(xv, Wk1[f * D + lane], ak);
    }
    hqs[wave][lane] = fmaxf(aq, 0.f);
    hks[wave][lane] = fmaxf(ak, 0.f);
    __syncthreads();

    float oq = bq2[lane], ok = bk2[lane];
    for (int t = 0; t < D; ++t) {
        oq = fmaf(hqs[wave][t], Wq2[t * D + lane], oq);
        ok = fmaf(hks[wave][t], Wk2[t * D + lane], ok);
    }
    qo[row * D + lane] = (_Float16)oq;
    ko[row * D + lane] = (_Float16)ok;
}

// ---------------- Pass 1: raw row max -> mpart[SPLIT][N] ----------------
// Wave owns 64 rows (4 row-groups); 16 MFMA per 4 k-loads.
__global__ __launch_bounds__(256) void k_max(
    const _Float16* __restrict__ q16, const _Float16* __restrict__ k16,
    float* __restrict__ mpart)
{
    const int tid  = threadIdx.x;
    const int wave = tid >> 6;
    const int lane = tid & 63;
    const int lr   = lane & 15;
    const int lg   = lane >> 4;
    const int i0   = blockIdx.x * BROWS + wave * 64;
    const int jbase = blockIdx.y * (N / SPLIT);

    f16x8 b[RG][2];
    #pragma unroll
    for (int rg = 0; rg < RG; ++rg) {
        b[rg][0] = *reinterpret_cast<const f16x8*>(&q16[(i0 + rg * 16 + lr) * D + 8 * lg]);
        b[rg][1] = *reinterpret_cast<const f16x8*>(&q16[(i0 + rg * 16 + lr) * D + 32 + 8 * lg]);
    }

    float mx[RG];
    #pragma unroll
    for (int rg = 0; rg < RG; ++rg) mx[rg] = -INFINITY;

    for (int cf = 0; cf < (N / SPLIT) / 32; ++cf) {
        const int j0 = jbase + cf * 32;
        #pragma unroll
        for (int rf = 0; rf < 2; ++rf) {
            const f16x8 a0 = *reinterpret_cast<const f16x8*>(&k16[(j0 + rf * 16 + lr) * D + 8 * lg]);
            const f16x8 a1 = *reinterpret_cast<const f16x8*>(&k16[(j0 + rf * 16 + lr) * D + 32 + 8 * lg]);
            #pragma unroll
            for (int rg = 0; rg < RG; ++rg) {
                f32x4 acc = {0.f, 0.f, 0.f, 0.f};
                acc = MFMA16(a0, b[rg][0], acc);
                acc = MFMA16(a1, b[rg][1], acc);
                mx[rg] = fmaxf(mx[rg], fmaxf(fmaxf(acc[0], acc[1]), fmaxf(acc[2], acc[3])));
            }
        }
    }

    #pragma unroll
    for (int rg = 0; rg < RG; ++rg) {
        mx[rg] = fmaxf(mx[rg], __shfl_xor(mx[rg], 16));
        mx[rg] = fmaxf(mx[rg], __shfl_xor(mx[rg], 32));
    }
    if (lane < 16) {
        #pragma unroll
        for (int rg = 0; rg < RG; ++rg)
            mpart[blockIdx.y * N + i0 + rg * 16 + lr] = mx[rg];
    }
}

// ---------------- rinv[j] = TEMP*log2e / m_j ----------------
__global__ __launch_bounds__(256) void k_fin1(const float* __restrict__ mp, float* __restrict__ rinv)
{
    const int j = blockIdx.x * 256 + threadIdx.x;
    float m = mp[j];
    #pragma unroll
    for (int s = 1; s < SPLIT; ++s) m = fmaxf(m, mp[s * N + j]);
    rinv[j] = TEMP * LOG2E / m;
}

// ---------------- Pass 2: scaled row max + sum -> M2part, Lpart ----------------
__global__ __launch_bounds__(256) void k_sumL(
    const _Float16* __restrict__ q16, const _Float16* __restrict__ k16,
    const float* __restrict__ rinv,
    float* __restrict__ M2part, float* __restrict__ Lpart)
{
    const int tid  = threadIdx.x;
    const int wave = tid >> 6;
    const int lane = tid & 63;
    const int lr   = lane & 15;
    const int lg   = lane >> 4;
    const int i0   = blockIdx.x * BROWS + wave * 64;
    const int jbase = blockIdx.y * (N / SPLIT);

    f16x8 b[RG][2];
    #pragma unroll
    for (int rg = 0; rg < RG; ++rg) {
        b[rg][0] = *reinterpret_cast<const f16x8*>(&q16[(i0 + rg * 16 + lr) * D + 8 * lg]);
        b[rg][1] = *reinterpret_cast<const f16x8*>(&q16[(i0 + rg * 16 + lr) * D + 32 + 8 * lg]);
    }

    float mx[RG], sm[RG];
    #pragma unroll
    for (int rg = 0; rg < RG; ++rg) { mx[rg] = -INFINITY; sm[rg] = 0.f; }

    for (int cf = 0; cf < (N / SPLIT) / 32; ++cf) {
        const int j0 = jbase + cf * 32;
        f32x4 acc[RG][2];
        float4 r4[2];
        #pragma unroll
        for (int rf = 0; rf < 2; ++rf) {
            const f16x8 a0 = *reinterpret_cast<const f16x8*>(&k16[(j0 + rf * 16 + lr) * D + 8 * lg]);
            const f16x8 a1 = *reinterpret_cast<const f16x8*>(&k16[(j0 + rf * 16 + lr) * D + 32 + 8 * lg]);
            r4[rf] = *reinterpret_cast<const float4*>(&rinv[j0 + rf * 16 + lg * 4]);
            #pragma unroll
            for (int rg = 0; rg < RG; ++rg) {
                f32x4 t = {0.f, 0.f, 0.f, 0.f};
                t = MFMA16(a0, b[rg][0], t);
                t = MFMA16(a1, b[rg][1], t);
                acc[rg][rf] = t;
            }
        }
        #pragma unroll
        for (int rg = 0; rg < RG; ++rg) {
            float s[8];
            s[0] = acc[rg][0][0] * r4[0].x; s[1] = acc[rg][0][1] * r4[0].y;
            s[2] = acc[rg][0][2] * r4[0].z; s[3] = acc[rg][0][3] * r4[0].w;
            s[4] = acc[rg][1][0] * r4[1].x; s[5] = acc[rg][1][1] * r4[1].y;
            s[6] = acc[rg][1][2] * r4[1].z; s[7] = acc[rg][1][3] * r4[1].w;
            const float tm = fmaxf(fmaxf(fmaxf(s[0], s[1]), fmaxf(s[2], s[3])),
                                   fmaxf(fmaxf(s[4], s[5]), fmaxf(s[6], s[7])));
            const float nm = fmaxf(mx[rg], tm);
            float add = 0.f;
            #pragma unroll
            for (int t = 0; t < 8; ++t) add += exp2f(s[t] - nm);
            sm[rg] = fmaf(sm[rg], exp2f(mx[rg] - nm), add);
            mx[rg] = nm;
        }
    }

    #pragma unroll
    for (int rg = 0; rg < RG; ++rg) {
        #pragma unroll
        for (int off = 16; off <= 32; off <<= 1) {
            const float om = __shfl_xor(mx[rg], off);
            const float os = __shfl_xor(sm[rg], off);
            const float nm = fmaxf(mx[rg], om);
            sm[rg] = sm[rg] * exp2f(mx[rg] - nm) + os * exp2f(om - nm);
            mx[rg] = nm;
        }
    }
    if (lane < 16) {
        #pragma unroll
        for (int rg = 0; rg < RG; ++rg) {
            M2part[blockIdx.y * N + i0 + rg * 16 + lr] = mx[rg];
            Lpart [blockIdx.y * N + i0 + rg * 16 + lr] = sm[rg];
        }
    }
}

// ---------------- M2[i], Linv[i] from split partials ----------------
__global__ __launch_bounds__(256) void k_finML(
    const float* __restrict__ M2p, const float* __restrict__ Lp,
    float* __restrict__ M2, float* __restrict__ Linv)
{
    const int i = blockIdx.x * 256 + threadIdx.x;
    float M = M2p[i];
    #pragma unroll
    for (int s = 1; s < SPLIT; ++s) M = fmaxf(M, M2p[s * N + i]);
    float L = 0.f;
    #pragma unroll
    for (int s = 0; s < SPLIT; ++s) L += Lp[s * N + i] * exp2f(M2p[s * N + i] - M);
    M2[i] = M;
    Linv[i] = 1.f / L;
}

// ---------------- Pass 3: out = exp2(s2 - M2_i) * Linv_i ----------------
// grid (N/256, 16); wave computes 64 rows x 512 cols; float4 stores.
__global__ __launch_bounds__(256) void k_write(
    const _Float16* __restrict__ q16, const _Float16* __restrict__ k16,
    const float* __restrict__ rinv, const float* __restrict__ M2,
    const float* __restrict__ Linv, float* __restrict__ out)
{
    const int tid  = threadIdx.x;
    const int wave = tid >> 6;
    const int lane = tid & 63;
    const int lr   = lane & 15;
    const int lg   = lane >> 4;
    const int i0   = blockIdx.x * BROWS + wave * 64;
    const int jbase = blockIdx.y * (N / 16);

    f16x8 b[RG][2];
    float M2i[RG], Lvi[RG];
    #pragma unroll
    for (int rg = 0; rg < RG; ++rg) {
        b[rg][0] = *reinterpret_cast<const f16x8*>(&q16[(i0 + rg * 16 + lr) * D + 8 * lg]);
        b[rg][1] = *reinterpret_cast<const f16x8*>(&q16[(i0 + rg * 16 + lr) * D + 32 + 8 * lg]);
        M2i[rg] = M2[i0 + rg * 16 + lr];
        Lvi[rg] = Linv[i0 + rg * 16 + lr];
    }

    for (int cf = 0; cf < (N / 16) / 32; ++cf) {
        const int j0 = jbase + cf * 32;
        #pragma unroll
        for (int rf = 0; rf < 2; ++rf) {
            const f16x8 a0 = *reinterpret_cast<const f16x8*>(&k16[(j0 + rf * 16 + lr) * D + 8 * lg]);
            const f16x8 a1 = *reinterpret_cast<const f16x8*>(&k16[(j0 + rf * 16 + lr) * D + 32 + 8 * lg]);
            const float4 r4 = *reinterpret_cast<const float4*>(&rinv[j0 + rf * 16 + lg * 4]);
            #pragma unroll
            for (int rg = 0; rg < RG; ++rg) {
                f32x4 acc = {0.f, 0.f, 0.f, 0.f};
                acc = MFMA16(a0, b[rg][0], acc);
                acc = MFMA16(a1, b[rg][1], acc);
                float4 o;
                o.x = exp2f(fmaf(acc[0], r4.x, -M2i[rg])) * Lvi[rg];
                o.y = exp2f(fmaf(acc[1], r4.y, -M2i[rg])) * Lvi[rg];
                o.z = exp2f(fmaf(acc[2], r4.z, -M2i[rg])) * Lvi[rg];
                o.w = exp2f(fmaf(acc[3], r4.w, -M2i[rg])) * Lvi[rg];
                *reinterpret_cast<float4*>(
                    &out[(size_t)(i0 + rg * 16 + lr) * N + j0 + rf * 16 + lg * 4]) = o;
            }
        }
    }
}

extern "C" void kernel_launch(void* const* d_in, const int* in_sizes, int n_in,
                              void* d_out, int out_size, void* d_ws, size_t ws_size,
                              hipStream_t stream)
{
    const float* x   = (const float*)d_in[0];
    const float* Wq1 = (const float*)d_in[1];
    const float* bq1 = (const float*)d_in[2];
    const float* Wq2 = (const float*)d_in[3];
    const float* bq2 = (const float*)d_in[4];
    const float* Wk1 = (const float*)d_in[5];
    const float* bk1 = (const float*)d_in[6];
    const float* Wk2 = (const float*)d_in[7];
    const float* bk2 = (const float*)d_in[8];

    float* out = (float*)d_out;

    _Float16* q16 = (_Float16*)d_ws;                       // 1 MB
    _Float16* k16 = q16 + (size_t)N * D;                   // 1 MB
    float* mpart  = (float*)(k16 + (size_t)N * D);         // SPLIT*N
    float* M2part = mpart + (size_t)SPLIT * N;             // SPLIT*N
    float* Lpart  = M2part + (size_t)SPLIT * N;            // SPLIT*N
    float* rinv   = Lpart + (size_t)SPLIT * N;             // N
    float* M2     = rinv + N;                              // N
    float* Linv   = M2 + N;                                // N

    k_mlp  <<<N / 4, 256, 0, stream>>>(x, Wq1, bq1, Wq2, bq2, Wk1, bk1, Wk2, bk2, q16, k16);
    k_max  <<<dim3(N / BROWS, SPLIT), 256, 0, stream>>>(q16, k16, mpart);
    k_fin1 <<<N / 256, 256, 0, stream>>>(mpart, rinv);
    k_sumL <<<dim3(N / BROWS, SPLIT), 256, 0, stream>>>(q16, k16, rinv, M2part, Lpart);
    k_finML<<<N / 256, 256, 0, stream>>>(M2part, Lpart, M2, Linv);
    k_write<<<dim3(N / BROWS, 16), 256, 0, stream>>>(q16, k16, rinv, M2, Linv, out);
}